// Round 10
// baseline (332.130 us; speedup 1.0000x reference)
//
#include <hip/hip_runtime.h>
#include <hip/hip_bf16.h>

// KascadeReuseAttention  B=1, S=2048, DM=1024, H=16, D=64, T=16, NA=3
// Round-10: persistent fused kernel with a MANUAL grid barrier (r9's
// hipLaunchCooperativeKernel never executed - unchecked launch error,
// likely coop-occupancy validation rejecting 768 blocks). 512 blocks,
// __launch_bounds__(256,2): 2 blocks/CU with >=3x margin on every
// resource -> co-residency guaranteed; barrier = monotonic device-scope
// counter in d_ws (memset to 0 on-stream each call, capture-safe) +
// __threadfence release/acquire for cross-XCD visibility (G16).

#define S_LEN 2048
#define DM 1024
#define NH 16
#define HD 64
#define LDK 40  // LDS row stride (ushorts); 80 B: 16B-aligned, 0 conflicts (measured)
#define NBLK 512

typedef __bf16 bf16x8 __attribute__((ext_vector_type(8)));
typedef float f32x4 __attribute__((ext_vector_type(4)));

static __device__ __forceinline__ unsigned short f2bf(float f) {
    union { float f; unsigned int i; } un;
    un.f = f;
    unsigned int r = un.i + 0x7FFFu + ((un.i >> 16) & 1u);  // RNE
    return (unsigned short)(r >> 16);
}
static __device__ __forceinline__ float bfu2f(unsigned short u) {
    union { unsigned int i; float f; } un;
    un.i = ((unsigned int)u) << 16;
    return un.f;
}
static __device__ __forceinline__ float bflo(unsigned int u) {
    union { unsigned int i; float f; } un;
    un.i = u << 16;
    return un.f;
}
static __device__ __forceinline__ float bfhi(unsigned int u) {
    union { unsigned int i; float f; } un;
    un.i = u & 0xFFFF0000u;
    return un.f;
}

// grid barrier: all NBLK blocks arrive; pass when counter reaches phase*NBLK.
static __device__ __forceinline__ void gbar(unsigned int* bar, unsigned int target) {
    __syncthreads();
    if (threadIdx.x == 0) {
        __threadfence();  // release: my global writes visible device-wide
        atomicAdd(bar, 1u);
        while (__hip_atomic_load(bar, __ATOMIC_RELAXED,
                                 __HIP_MEMORY_SCOPE_AGENT) < target)
            __builtin_amdgcn_s_sleep(8);
        __threadfence();  // acquire: others' writes visible to me
    }
    __syncthreads();
}

__global__ __launch_bounds__(256, 2) void fused(
    const float* __restrict__ x,
    const float* __restrict__ Wq, const float* __restrict__ Wk,
    const float* __restrict__ Wv, const float* __restrict__ Wo,
    const float* __restrict__ cs, const float* __restrict__ sn,
    const int* __restrict__ anc, float* __restrict__ out,
    unsigned int* __restrict__ bar,
    unsigned short* __restrict__ xb,
    unsigned short* __restrict__ Wtq, unsigned short* __restrict__ Wtk,
    unsigned short* __restrict__ Wtv, unsigned short* __restrict__ Wto,
    unsigned short* __restrict__ qh, unsigned short* __restrict__ kh,
    unsigned short* __restrict__ vh, unsigned short* __restrict__ att) {
    __shared__ __align__(16) unsigned char smem[15360];
    const int bid = blockIdx.x;
    const int tid = threadIdx.x;
    const int lane = tid & 63, wvi = tid >> 6;
    const int l15 = lane & 15, quad = lane >> 4;

    // ---------------- stage 0: prep (transpose W -> bf16 [n][k]; convert x)
    {
        float (*t)[33] = (float(*)[33])smem;
        for (int u = bid; u < 5120; u += NBLK) {
            if (u < 4096) {
                const int z = u >> 10, rem = u & 1023;
                const float* W = (z == 0) ? Wq : (z == 1) ? Wk : (z == 2) ? Wv : Wo;
                unsigned short* T = (z == 0) ? Wtq : (z == 1) ? Wtk : (z == 2) ? Wtv : Wto;
                const int bn = (rem & 31) * 32, bk = (rem >> 5) * 32;
                const int tx = tid & 31, ty = tid >> 5;
                #pragma unroll
                for (int m = 0; m < 4; ++m)
                    t[ty + m * 8][tx] = W[(size_t)(bk + ty + m * 8) * 1024 + bn + tx];
                __syncthreads();
                #pragma unroll
                for (int m = 0; m < 4; ++m)
                    T[(size_t)(bn + ty + m * 8) * 1024 + bk + tx] = f2bf(t[tx][ty + m * 8]);
                __syncthreads();  // protect t before next iteration's writes
            } else {
                const int i = (u - 4096) * 2048 + tid * 8;
                float4 f0 = *(const float4*)(x + i);
                float4 f1 = *(const float4*)(x + i + 4);
                ushort4 o0, o1;
                o0.x = f2bf(f0.x); o0.y = f2bf(f0.y); o0.z = f2bf(f0.z); o0.w = f2bf(f0.w);
                o1.x = f2bf(f1.x); o1.y = f2bf(f1.y); o1.z = f2bf(f1.z); o1.w = f2bf(f1.w);
                *(ushort4*)(xb + i) = o0;
                *(ushort4*)(xb + i + 4) = o1;
            }
        }
    }
    gbar(bar, 1u * NBLK);

    // ---------------- stage 1: QKV GEMM, 64x128 tile, 768 units strided
    {
        unsigned short* Al = (unsigned short*)smem;              // 64*LDK
        unsigned short* Bl = Al + 64 * LDK;                      // 128*LDK
        const int wr = (wvi >> 1) * 32, wc = (wvi & 1) * 64;
        const int rowA = tid >> 2, kqA = (tid & 3) << 3;   // 8 el/thread
        const int rowB = tid >> 1, kqB = (tid & 1) << 4;   // 16 el/thread
        for (int u = bid; u < 768; u += NBLK) {
            const int nb = u >> 8;                  // 0..2 : q/k/v
            const int rem = u & 255;
            const int col0 = ((rem >> 5) & 7) * 128;
            const int row0 = (rem & 31) * 64;
            const unsigned short* __restrict__ Bt = (nb == 0) ? Wtq : (nb == 1) ? Wtk : Wtv;
            unsigned short* __restrict__ OUT = (nb == 0) ? qh : (nb == 1) ? kh : vh;

            f32x4 acc[2][4] = {};
            for (int k0 = 0; k0 < 1024; k0 += 32) {
                const uint4 a0 = *(const uint4*)(xb + (size_t)(row0 + rowA) * 1024 + k0 + kqA);
                const unsigned short* gb = Bt + (size_t)(col0 + rowB) * 1024 + k0 + kqB;
                const uint4 b0 = *(const uint4*)gb;
                const uint4 b1 = *(const uint4*)(gb + 8);
                __syncthreads();
                *(uint4*)&Al[rowA * LDK + kqA] = a0;
                unsigned short* bd = &Bl[rowB * LDK + kqB];
                *(uint4*)bd = b0; *(uint4*)(bd + 8) = b1;
                __syncthreads();
                bf16x8 af[2], bfr[4];
                #pragma unroll
                for (int i = 0; i < 2; ++i)
                    af[i] = *(const bf16x8*)&Al[(wr + i * 16 + l15) * LDK + quad * 8];
                #pragma unroll
                for (int j = 0; j < 4; ++j)
                    bfr[j] = *(const bf16x8*)&Bl[(wc + j * 16 + l15) * LDK + quad * 8];
                #pragma unroll
                for (int i = 0; i < 2; ++i)
                    #pragma unroll
                    for (int j = 0; j < 4; ++j)
                        acc[i][j] = __builtin_amdgcn_mfma_f32_16x16x32_bf16(
                            af[i], bfr[j], acc[i][j], 0, 0, 0);
            }
            // epilogue: wave's 64 cols = one head; fused RoPE; head-major store
            const int hh = (((rem >> 5) & 7) << 1) + (wc >> 6);
            const bool dorope = (nb != 2);
            #pragma unroll
            for (int i = 0; i < 2; ++i) {
                const int rowb = row0 + wr + i * 16 + quad * 4;
                #pragma unroll
                for (int r = 0; r < 4; ++r) {
                    const int s = rowb + r;
                    float v0 = acc[i][0][r], v1 = acc[i][1][r];
                    float v2 = acc[i][2][r], v3 = acc[i][3][r];
                    if (dorope) {
                        float c0 = cs[s * 32 + l15],      s0 = sn[s * 32 + l15];
                        float c1 = cs[s * 32 + 16 + l15], s1 = sn[s * 32 + 16 + l15];
                        float lo0 = v0 * c0 - v2 * s0;
                        float hi0 = v2 * c0 + v0 * s0;
                        float lo1 = v1 * c1 - v3 * s1;
                        float hi1 = v3 * c1 + v1 * s1;
                        v0 = lo0; v1 = lo1; v2 = hi0; v3 = hi1;
                    }
                    unsigned short* op = OUT + (size_t)hh * (S_LEN * 64) + (size_t)s * 64 + l15;
                    op[0]  = f2bf(v0);
                    op[16] = f2bf(v1);
                    op[32] = f2bf(v2);
                    op[48] = f2bf(v3);
                }
            }
            __syncthreads();  // protect Al/Bl before next unit's staging
        }
    }
    gbar(bar, 2u * NBLK);

    // ---------------- stage 2: attention (r8 dataflow), 8192 units strided
    {
        float* qs = (float*)smem;                 // [4][64]
        int*   ts = (int*)(smem + 1024);          // [4][64]
        float* ws = (float*)(smem + 2048);        // [4][64]
        const int c = lane & 3;
        const int t = lane >> 2;
        for (int u = bid; u < 8192; u += NBLK) {
            const int wid = (u << 2) + wvi;
            const int h = wid >> 11;
            const int qi = wid & 2047;
            const size_t hb = (size_t)h * (S_LEN * 64);

            // phase 1: stage q + token into this wave's LDS slice
            const float q_own = bfu2f(qh[hb + (size_t)qi * 64 + lane]);
            const int slot = lane >> 4;
            const int tile = (slot < 3) ? anc[((size_t)h * S_LEN + qi) * 3 + slot]
                                        : (qi >> 4);
            const int tok_own = tile * 16 + (lane & 15);
            qs[wvi * 64 + lane] = q_own;
            ts[wvi * 64 + lane] = tok_own;

            float qv[16];
            #pragma unroll
            for (int r = 0; r < 4; ++r) {
                float4 f = *(const float4*)&qs[wvi * 64 + c * 16 + r * 4];
                qv[r * 4 + 0] = f.x; qv[r * 4 + 1] = f.y;
                qv[r * 4 + 2] = f.z; qv[r * 4 + 3] = f.w;
            }

            // phase 2: 4 lanes/token, width-4 butterfly reduce
            #pragma unroll
            for (int p = 0; p < 4; ++p) {
                const int tk = ts[wvi * 64 + p * 16 + t];
                const unsigned short* kp = kh + hb + (size_t)tk * 64 + c * 16;
                const uint4 k0 = *(const uint4*)kp;
                const uint4 k1 = *(const uint4*)(kp + 8);
                float part;
                part = bflo(k0.x) * qv[0];
                part = fmaf(bfhi(k0.x), qv[1], part);
                part = fmaf(bflo(k0.y), qv[2], part);
                part = fmaf(bfhi(k0.y), qv[3], part);
                part = fmaf(bflo(k0.z), qv[4], part);
                part = fmaf(bfhi(k0.z), qv[5], part);
                part = fmaf(bflo(k0.w), qv[6], part);
                part = fmaf(bfhi(k0.w), qv[7], part);
                part = fmaf(bflo(k1.x), qv[8], part);
                part = fmaf(bfhi(k1.x), qv[9], part);
                part = fmaf(bflo(k1.y), qv[10], part);
                part = fmaf(bfhi(k1.y), qv[11], part);
                part = fmaf(bflo(k1.z), qv[12], part);
                part = fmaf(bfhi(k1.z), qv[13], part);
                part = fmaf(bflo(k1.w), qv[14], part);
                part = fmaf(bfhi(k1.w), qv[15], part);
                part += __shfl_xor(part, 1, 64);
                part += __shfl_xor(part, 2, 64);
                if (c == 0) ws[wvi * 64 + p * 16 + t] = part;
            }

            float logit = ws[wvi * 64 + lane];
            const bool fut = tok_own > qi;
            logit = fut ? -1e30f : logit * 0.125f;

            float m = logit;
            #pragma unroll
            for (int off = 32; off >= 1; off >>= 1)
                m = fmaxf(m, __shfl_xor(m, off, 64));
            const float e = fut ? 0.f : __expf(logit - m);
            float ssum = e;
            #pragma unroll
            for (int off = 32; off >= 1; off >>= 1)
                ssum += __shfl_xor(ssum, off, 64);
            ws[wvi * 64 + lane] = e / ssum;

            // phase 4: lane = dim; addresses from ts (early), named scalars
            const unsigned short* vb = vh + hb + lane;
            float o = 0.f;
            #pragma unroll
            for (int kk = 0; kk < 64; kk += 8) {
                const int4 ta = *(const int4*)&ts[wvi * 64 + kk];
                const int4 tb = *(const int4*)&ts[wvi * 64 + kk + 4];
                const float v0 = bfu2f(vb[(size_t)ta.x * 64]);
                const float v1 = bfu2f(vb[(size_t)ta.y * 64]);
                const float v2 = bfu2f(vb[(size_t)ta.z * 64]);
                const float v3 = bfu2f(vb[(size_t)ta.w * 64]);
                const float v4 = bfu2f(vb[(size_t)tb.x * 64]);
                const float v5 = bfu2f(vb[(size_t)tb.y * 64]);
                const float v6 = bfu2f(vb[(size_t)tb.z * 64]);
                const float v7 = bfu2f(vb[(size_t)tb.w * 64]);
                const float4 wa = *(const float4*)&ws[wvi * 64 + kk];
                const float4 wb = *(const float4*)&ws[wvi * 64 + kk + 4];
                o = fmaf(wa.x, v0, o);
                o = fmaf(wa.y, v1, o);
                o = fmaf(wa.z, v2, o);
                o = fmaf(wa.w, v3, o);
                o = fmaf(wb.x, v4, o);
                o = fmaf(wb.y, v5, o);
                o = fmaf(wb.z, v6, o);
                o = fmaf(wb.w, v7, o);
            }
            att[(size_t)qi * DM + h * HD + lane] = f2bf(o);
        }
    }
    gbar(bar, 3u * NBLK);

    // ---------------- stage 3: out GEMM, 64x64 tile, 512 units (1/block)
    {
        unsigned short* Al = (unsigned short*)smem;              // 64*LDK
        unsigned short* Bl = Al + 64 * LDK;                      // 64*LDK
        const int col0 = (bid & 15) * 64;
        const int row0 = (bid >> 4) * 64;
        const int wr = (wvi >> 1) * 32, wc = (wvi & 1) * 32;
        const int rowA = tid >> 2, kqA = (tid & 3) << 3;   // 8 el/thread

        f32x4 acc[2][2] = {};
        for (int k0 = 0; k0 < 1024; k0 += 32) {
            const uint4 a0 = *(const uint4*)(att + (size_t)(row0 + rowA) * 1024 + k0 + kqA);
            const uint4 b0 = *(const uint4*)(Wto + (size_t)(col0 + rowA) * 1024 + k0 + kqA);
            __syncthreads();
            *(uint4*)&Al[rowA * LDK + kqA] = a0;
            *(uint4*)&Bl[rowA * LDK + kqA] = b0;
            __syncthreads();
            bf16x8 af[2], bfr[2];
            #pragma unroll
            for (int i = 0; i < 2; ++i)
                af[i] = *(const bf16x8*)&Al[(wr + i * 16 + l15) * LDK + quad * 8];
            #pragma unroll
            for (int j = 0; j < 2; ++j)
                bfr[j] = *(const bf16x8*)&Bl[(wc + j * 16 + l15) * LDK + quad * 8];
            #pragma unroll
            for (int i = 0; i < 2; ++i)
                #pragma unroll
                for (int j = 0; j < 2; ++j)
                    acc[i][j] = __builtin_amdgcn_mfma_f32_16x16x32_bf16(
                        af[i], bfr[j], acc[i][j], 0, 0, 0);
        }
        #pragma unroll
        for (int i = 0; i < 2; ++i) {
            const int rowb = row0 + wr + i * 16 + quad * 4;
            #pragma unroll
            for (int r = 0; r < 4; ++r) {
                float* crow = out + (size_t)(rowb + r) * 1024 + col0 + wc;
                #pragma unroll
                for (int j = 0; j < 2; ++j)
                    crow[j * 16 + l15] = acc[i][j][r];
            }
        }
    }
}

// ---------------------------------------------------------------------------
extern "C" void kernel_launch(void* const* d_in, const int* in_sizes, int n_in,
                              void* d_out, int out_size, void* d_ws, size_t ws_size,
                              hipStream_t stream) {
    const float* x   = (const float*)d_in[0];
    const float* Wq  = (const float*)d_in[1];
    const float* Wk  = (const float*)d_in[2];
    const float* Wv  = (const float*)d_in[3];
    const float* Wo  = (const float*)d_in[4];
    const float* cs  = (const float*)d_in[5];
    const float* sn  = (const float*)d_in[6];
    const int*   anc = (const int*)d_in[7];
    float* out = (float*)d_out;

    unsigned int*   bar = (unsigned int*)d_ws;              // 1 KB reserved
    unsigned short* xb  = (unsigned short*)d_ws + 512;      // 1 KB offset
    unsigned short* Wtq = xb  + (size_t)2048 * 1024;
    unsigned short* Wtk = Wtq + (size_t)1024 * 1024;
    unsigned short* Wtv = Wtk + (size_t)1024 * 1024;
    unsigned short* Wto = Wtv + (size_t)1024 * 1024;
    unsigned short* qh  = Wto + (size_t)1024 * 1024;        // [H][S][64]
    unsigned short* kh  = qh  + (size_t)2048 * 1024;
    unsigned short* vh  = kh  + (size_t)2048 * 1024;
    unsigned short* att = vh  + (size_t)2048 * 1024;        // [S][H*D]

    hipMemsetAsync(bar, 0, 1024, stream);  // zero barrier counter (capture-safe)
    fused<<<NBLK, 256, 0, stream>>>(x, Wq, Wk, Wv, Wo, cs, sn, anc, out, bar,
                                    xb, Wtq, Wtk, Wtv, Wto, qh, kh, vh, att);
}

// Round 11
// 162.312 us; speedup vs baseline: 2.0462x; 2.0462x over previous
//
#include <hip/hip_runtime.h>
#include <hip/hip_bf16.h>

// KascadeReuseAttention  B=1, S=2048, DM=1024, H=16, D=64, T=16, NA=3
// Round-11: r10 persistent fusion regressed 2x (occupancy capped at 8
// waves/CU -> latency-bound stages starved; 23.8% occupancy measured).
// Revert to r8's proven 4-launch structure; upgrade both GEMM K-loops to
// m97-style __builtin_amdgcn_global_load_lds width-16 staging (measured
// 1.69x on the learn_hip ladder): unpadded [row][k] bf16 LDS (64 B rows,
// GLL needs lane-contiguous dest; padding breaks it), 2-barrier K-loop.
// prep & attn kernels are r8-verbatim (frozen while not the top cost).

#define S_LEN 2048
#define DM 1024
#define NH 16
#define HD 64
#define NBLK 512

typedef __bf16 bf16x8 __attribute__((ext_vector_type(8)));
typedef float f32x4 __attribute__((ext_vector_type(4)));

static __device__ __forceinline__ unsigned short f2bf(float f) {
    union { float f; unsigned int i; } un;
    un.f = f;
    unsigned int r = un.i + 0x7FFFu + ((un.i >> 16) & 1u);  // RNE
    return (unsigned short)(r >> 16);
}
static __device__ __forceinline__ float bfu2f(unsigned short u) {
    union { unsigned int i; float f; } un;
    un.i = ((unsigned int)u) << 16;
    return un.f;
}
static __device__ __forceinline__ float bflo(unsigned int u) {
    union { unsigned int i; float f; } un;
    un.i = u << 16;
    return un.f;
}
static __device__ __forceinline__ float bfhi(unsigned int u) {
    union { unsigned int i; float f; } un;
    un.i = u & 0xFFFF0000u;
    return un.f;
}

// async global->LDS, 16 B per lane; LDS dest = uniform base + lane*16.
static __device__ __forceinline__ void gll16(const unsigned short* g,
                                             unsigned short* l) {
    __builtin_amdgcn_global_load_lds(
        (const __attribute__((address_space(1))) unsigned int*)(uintptr_t)g,
        (__attribute__((address_space(3))) unsigned int*)(uintptr_t)l,
        16, 0, 0);
}

// ---------------------------------------------------------------------------
// prep (r8-verbatim): blocks [0,4096) transpose W* fp32->bf16 [n][k];
// blocks [4096,5120) convert x fp32->bf16.
// ---------------------------------------------------------------------------
__global__ __launch_bounds__(256) void prep(
    const float* __restrict__ x, unsigned short* __restrict__ xb,
    const float* __restrict__ W0, const float* __restrict__ W1,
    const float* __restrict__ W2, const float* __restrict__ W3,
    unsigned short* __restrict__ T0, unsigned short* __restrict__ T1,
    unsigned short* __restrict__ T2, unsigned short* __restrict__ T3) {
    const int bx = blockIdx.x;
    if (bx < 4096) {
        const int z = bx >> 10, rem = bx & 1023;
        const float* W = (z == 0) ? W0 : (z == 1) ? W1 : (z == 2) ? W2 : W3;
        unsigned short* T = (z == 0) ? T0 : (z == 1) ? T1 : (z == 2) ? T2 : T3;
        __shared__ float t[32][33];
        const int bn = (rem & 31) * 32, bk = (rem >> 5) * 32;
        const int tx = threadIdx.x & 31, ty = threadIdx.x >> 5;
        #pragma unroll
        for (int m = 0; m < 4; ++m)
            t[ty + m * 8][tx] = W[(size_t)(bk + ty + m * 8) * 1024 + bn + tx];
        __syncthreads();
        #pragma unroll
        for (int m = 0; m < 4; ++m)
            T[(size_t)(bn + ty + m * 8) * 1024 + bk + tx] = f2bf(t[tx][ty + m * 8]);
    } else {
        const int i = (bx - 4096) * 2048 + threadIdx.x * 8;
        float4 f0 = *(const float4*)(x + i);
        float4 f1 = *(const float4*)(x + i + 4);
        ushort4 o0, o1;
        o0.x = f2bf(f0.x); o0.y = f2bf(f0.y); o0.z = f2bf(f0.z); o0.w = f2bf(f0.w);
        o1.x = f2bf(f1.x); o1.y = f2bf(f1.y); o1.z = f2bf(f1.z); o1.w = f2bf(f1.w);
        *(ushort4*)(xb + i) = o0;
        *(ushort4*)(xb + i + 4) = o1;
    }
}

// ---------------------------------------------------------------------------
// QKV GEMM: 128x128 tile, BK=32, grid (24,16), m97-style global_load_lds
// staging (unpadded LDS, 64 B rows). Fused RoPE epilogue, head-major bf16
// out [H][S][64].
// ---------------------------------------------------------------------------
__global__ __launch_bounds__(256) void gemm_qkv(
    const unsigned short* __restrict__ xb,
    const unsigned short* __restrict__ Wtq, const unsigned short* __restrict__ Wtk,
    const unsigned short* __restrict__ Wtv,
    unsigned short* __restrict__ qh, unsigned short* __restrict__ kh,
    unsigned short* __restrict__ vh,
    const float* __restrict__ cs, const float* __restrict__ sn) {
    __shared__ __align__(16) unsigned short Al[128 * 32];
    __shared__ __align__(16) unsigned short Bl[128 * 32];
    const int tid = threadIdx.x;
    const int nb = blockIdx.x >> 3;
    const unsigned short* __restrict__ Bt = (nb == 0) ? Wtq : (nb == 1) ? Wtk : Wtv;
    unsigned short* __restrict__ OUT = (nb == 0) ? qh : (nb == 1) ? kh : vh;
    const int col0 = (blockIdx.x & 7) * 128;
    const int row0 = blockIdx.y * 128;
    const int lane = tid & 63, wvi = tid >> 6;
    const int wr = (wvi >> 1) * 64, wc = (wvi & 1) * 64;
    const int l15 = lane & 15, quad = lane >> 4;

    // GLL addressing: wave stages 32 rows of A and 32 of B per k-iter,
    // 2 instr each (16 rows/instr; lane i -> row i>>2, 16B chunk i&3).
    const int grow = lane >> 2;            // 0..15
    const int gkc = (lane & 3) * 8;        // element offset within row
    const unsigned short* gA = xb + (size_t)(row0 + wvi * 32 + grow) * 1024 + gkc;
    const unsigned short* gB = Bt + (size_t)(col0 + wvi * 32 + grow) * 1024 + gkc;
    unsigned short* lA = Al + (wvi * 32) * 32;   // wave-uniform LDS base
    unsigned short* lB = Bl + (wvi * 32) * 32;

    f32x4 acc[4][4] = {};
    for (int k0 = 0; k0 < 1024; k0 += 32) {
        __syncthreads();  // prior iter's ds_reads complete before overwrite
        gll16(gA + k0, lA);
        gll16(gA + 16 * 1024 + k0, lA + 16 * 32);
        gll16(gB + k0, lB);
        gll16(gB + 16 * 1024 + k0, lB + 16 * 32);
        __syncthreads();  // drains vmcnt(0): GLL data landed
        bf16x8 af[4], bfr[4];
        #pragma unroll
        for (int i = 0; i < 4; ++i)
            af[i] = *(const bf16x8*)&Al[(wr + i * 16 + l15) * 32 + quad * 8];
        #pragma unroll
        for (int j = 0; j < 4; ++j)
            bfr[j] = *(const bf16x8*)&Bl[(wc + j * 16 + l15) * 32 + quad * 8];
        #pragma unroll
        for (int i = 0; i < 4; ++i)
            #pragma unroll
            for (int j = 0; j < 4; ++j)
                acc[i][j] = __builtin_amdgcn_mfma_f32_16x16x32_bf16(
                    af[i], bfr[j], acc[i][j], 0, 0, 0);
    }

    // epilogue: wave's 64 cols = one head; fused RoPE; head-major store
    const int hh = ((blockIdx.x & 7) << 1) + (wc >> 6);
    const bool dorope = (nb != 2);
    #pragma unroll
    for (int i = 0; i < 4; ++i) {
        const int rowb = row0 + wr + i * 16 + quad * 4;
        #pragma unroll
        for (int r = 0; r < 4; ++r) {
            const int s = rowb + r;
            float v0 = acc[i][0][r], v1 = acc[i][1][r];
            float v2 = acc[i][2][r], v3 = acc[i][3][r];
            if (dorope) {
                float c0 = cs[s * 32 + l15],      s0 = sn[s * 32 + l15];
                float c1 = cs[s * 32 + 16 + l15], s1 = sn[s * 32 + 16 + l15];
                float lo0 = v0 * c0 - v2 * s0;
                float hi0 = v2 * c0 + v0 * s0;
                float lo1 = v1 * c1 - v3 * s1;
                float hi1 = v3 * c1 + v1 * s1;
                v0 = lo0; v1 = lo1; v2 = hi0; v3 = hi1;
            }
            unsigned short* op = OUT + (size_t)hh * (S_LEN * 64) + (size_t)s * 64 + l15;
            op[0]  = f2bf(v0);
            op[16] = f2bf(v1);
            op[32] = f2bf(v2);
            op[48] = f2bf(v3);
        }
    }
}

// ---------------------------------------------------------------------------
// Attention (r8-verbatim): one wave per (h,q). Wave-private LDS slices;
// same-address broadcast ds_reads; phase-4 addresses from ts (early).
// ---------------------------------------------------------------------------
__global__ __launch_bounds__(256) void attn_kernel(
    const unsigned short* __restrict__ qh, const unsigned short* __restrict__ kh,
    const unsigned short* __restrict__ vh, const int* __restrict__ anc,
    unsigned short* __restrict__ att) {
    __shared__ __align__(16) float qs[4][64];
    __shared__ __align__(16) int   ts[4][64];
    __shared__ __align__(16) float ws[4][64];
    const int w4 = threadIdx.x >> 6;
    const int lane = threadIdx.x & 63;
    const int wid = (blockIdx.x << 2) + w4;
    const int h = wid >> 11;
    const int qi = wid & 2047;
    const size_t hb = (size_t)h * (S_LEN * 64);

    const float q_own = bfu2f(qh[hb + (size_t)qi * 64 + lane]);
    const int slot = lane >> 4;
    const int tile = (slot < 3) ? anc[((size_t)h * S_LEN + qi) * 3 + slot]
                                : (qi >> 4);
    const int tok_own = tile * 16 + (lane & 15);
    qs[w4][lane] = q_own;
    ts[w4][lane] = tok_own;

    const int c = lane & 3;
    const int t = lane >> 2;
    float qv[16];
    #pragma unroll
    for (int r = 0; r < 4; ++r) {
        float4 f = *(const float4*)&qs[w4][c * 16 + r * 4];
        qv[r * 4 + 0] = f.x; qv[r * 4 + 1] = f.y;
        qv[r * 4 + 2] = f.z; qv[r * 4 + 3] = f.w;
    }

    #pragma unroll
    for (int p = 0; p < 4; ++p) {
        const int tk = ts[w4][p * 16 + t];
        const unsigned short* kp = kh + hb + (size_t)tk * 64 + c * 16;
        const uint4 k0 = *(const uint4*)kp;
        const uint4 k1 = *(const uint4*)(kp + 8);
        float part;
        part = bflo(k0.x) * qv[0];
        part = fmaf(bfhi(k0.x), qv[1], part);
        part = fmaf(bflo(k0.y), qv[2], part);
        part = fmaf(bfhi(k0.y), qv[3], part);
        part = fmaf(bflo(k0.z), qv[4], part);
        part = fmaf(bfhi(k0.z), qv[5], part);
        part = fmaf(bflo(k0.w), qv[6], part);
        part = fmaf(bfhi(k0.w), qv[7], part);
        part = fmaf(bflo(k1.x), qv[8], part);
        part = fmaf(bfhi(k1.x), qv[9], part);
        part = fmaf(bflo(k1.y), qv[10], part);
        part = fmaf(bfhi(k1.y), qv[11], part);
        part = fmaf(bflo(k1.z), qv[12], part);
        part = fmaf(bfhi(k1.z), qv[13], part);
        part = fmaf(bflo(k1.w), qv[14], part);
        part = fmaf(bfhi(k1.w), qv[15], part);
        part += __shfl_xor(part, 1, 64);
        part += __shfl_xor(part, 2, 64);
        if (c == 0) ws[w4][p * 16 + t] = part;
    }

    float logit = ws[w4][lane];
    const bool fut = tok_own > qi;
    logit = fut ? -1e30f : logit * 0.125f;

    float m = logit;
    #pragma unroll
    for (int off = 32; off >= 1; off >>= 1)
        m = fmaxf(m, __shfl_xor(m, off, 64));
    const float e = fut ? 0.f : __expf(logit - m);
    float ssum = e;
    #pragma unroll
    for (int off = 32; off >= 1; off >>= 1)
        ssum += __shfl_xor(ssum, off, 64);
    ws[w4][lane] = e / ssum;

    const unsigned short* vb = vh + hb + lane;
    float out = 0.f;
    #pragma unroll
    for (int kk = 0; kk < 64; kk += 8) {
        const int4 ta = *(const int4*)&ts[w4][kk];
        const int4 tb = *(const int4*)&ts[w4][kk + 4];
        const float v0 = bfu2f(vb[(size_t)ta.x * 64]);
        const float v1 = bfu2f(vb[(size_t)ta.y * 64]);
        const float v2 = bfu2f(vb[(size_t)ta.z * 64]);
        const float v3 = bfu2f(vb[(size_t)ta.w * 64]);
        const float v4 = bfu2f(vb[(size_t)tb.x * 64]);
        const float v5 = bfu2f(vb[(size_t)tb.y * 64]);
        const float v6 = bfu2f(vb[(size_t)tb.z * 64]);
        const float v7 = bfu2f(vb[(size_t)tb.w * 64]);
        const float4 wa = *(const float4*)&ws[w4][kk];
        const float4 wb = *(const float4*)&ws[w4][kk + 4];
        out = fmaf(wa.x, v0, out);
        out = fmaf(wa.y, v1, out);
        out = fmaf(wa.z, v2, out);
        out = fmaf(wa.w, v3, out);
        out = fmaf(wb.x, v4, out);
        out = fmaf(wb.y, v5, out);
        out = fmaf(wb.z, v6, out);
        out = fmaf(wb.w, v7, out);
    }
    att[(size_t)qi * DM + h * HD + lane] = f2bf(out);
}

// ---------------------------------------------------------------------------
// Out GEMM: 64x128 tile, grid (8,32), global_load_lds staging.
// ---------------------------------------------------------------------------
__global__ __launch_bounds__(256) void gemm_out(
    const unsigned short* __restrict__ A, const unsigned short* __restrict__ Bt,
    float* __restrict__ C) {
    __shared__ __align__(16) unsigned short Al[64 * 32];
    __shared__ __align__(16) unsigned short Bl[128 * 32];
    const int tid = threadIdx.x;
    const int col0 = blockIdx.x * 128;
    const int row0 = blockIdx.y * 64;
    const int lane = tid & 63, wvi = tid >> 6;
    const int wr = (wvi >> 1) * 32, wc = (wvi & 1) * 64;
    const int l15 = lane & 15, quad = lane >> 4;

    const int grow = lane >> 2;
    const int gkc = (lane & 3) * 8;
    const unsigned short* gA = A + (size_t)(row0 + wvi * 16 + grow) * 1024 + gkc;
    const unsigned short* gB = Bt + (size_t)(col0 + wvi * 32 + grow) * 1024 + gkc;
    unsigned short* lA = Al + (wvi * 16) * 32;   // wave-uniform
    unsigned short* lB = Bl + (wvi * 32) * 32;

    f32x4 acc[2][4] = {};
    for (int k0 = 0; k0 < 1024; k0 += 32) {
        __syncthreads();
        gll16(gA + k0, lA);                       // A: 64 rows total
        gll16(gB + k0, lB);                       // B: 128 rows total
        gll16(gB + 16 * 1024 + k0, lB + 16 * 32);
        __syncthreads();
        bf16x8 af[2], bfr[4];
        #pragma unroll
        for (int i = 0; i < 2; ++i)
            af[i] = *(const bf16x8*)&Al[(wr + i * 16 + l15) * 32 + quad * 8];
        #pragma unroll
        for (int j = 0; j < 4; ++j)
            bfr[j] = *(const bf16x8*)&Bl[(wc + j * 16 + l15) * 32 + quad * 8];
        #pragma unroll
        for (int i = 0; i < 2; ++i)
            #pragma unroll
            for (int j = 0; j < 4; ++j)
                acc[i][j] = __builtin_amdgcn_mfma_f32_16x16x32_bf16(
                    af[i], bfr[j], acc[i][j], 0, 0, 0);
    }
    #pragma unroll
    for (int i = 0; i < 2; ++i) {
        const int rowb = row0 + wr + i * 16 + quad * 4;
        #pragma unroll
        for (int r = 0; r < 4; ++r) {
            float* crow = C + (size_t)(rowb + r) * 1024 + col0 + wc;
            #pragma unroll
            for (int j = 0; j < 4; ++j)
                crow[j * 16 + l15] = acc[i][j][r];
        }
    }
}

// ---------------------------------------------------------------------------
extern "C" void kernel_launch(void* const* d_in, const int* in_sizes, int n_in,
                              void* d_out, int out_size, void* d_ws, size_t ws_size,
                              hipStream_t stream) {
    const float* x   = (const float*)d_in[0];
    const float* Wq  = (const float*)d_in[1];
    const float* Wk  = (const float*)d_in[2];
    const float* Wv  = (const float*)d_in[3];
    const float* Wo  = (const float*)d_in[4];
    const float* cs  = (const float*)d_in[5];
    const float* sn  = (const float*)d_in[6];
    const int*   anc = (const int*)d_in[7];
    float* out = (float*)d_out;

    unsigned short* xb  = (unsigned short*)d_ws;
    unsigned short* Wtq = xb  + (size_t)2048 * 1024;
    unsigned short* Wtk = Wtq + (size_t)1024 * 1024;
    unsigned short* Wtv = Wtk + (size_t)1024 * 1024;
    unsigned short* Wto = Wtv + (size_t)1024 * 1024;
    unsigned short* qh  = Wto + (size_t)1024 * 1024;   // [H][S][64]
    unsigned short* kh  = qh  + (size_t)2048 * 1024;
    unsigned short* vh  = kh  + (size_t)2048 * 1024;
    unsigned short* att = vh  + (size_t)2048 * 1024;   // [S][H*D]

    prep<<<5120, 256, 0, stream>>>(x, xb, Wq, Wk, Wv, Wo, Wtq, Wtk, Wtv, Wto);
    gemm_qkv<<<dim3(24, 16), 256, 0, stream>>>(xb, Wtq, Wtk, Wtv,
                                               qh, kh, vh, cs, sn);
    attn_kernel<<<(S_LEN * NH) / 4, 256, 0, stream>>>(qh, kh, vh, anc, att);
    gemm_out<<<dim3(8, 32), 256, 0, stream>>>(att, Wto, out);
}